// Round 14
// baseline (215966.406 us; speedup 1.0000x reference)
//
#include <hip/hip_runtime.h>
#include <stdint.h>

#define DEV __device__ __forceinline__

typedef __attribute__((ext_vector_type(2))) float f32x2;

DEV float sigm(float x) { return 1.f / (1.f + __expf(-x)); }
DEV float tanh_fast(float x) {
    float e = __expf(-2.f * fabsf(x));
    float t = (1.f - e) / (1.f + e);
    return x < 0.f ? -t : t;
}

// ===========================================================================
// f32 GEMM engine v4: round-13 conflict-free fragment mapping
// + double-buffered LDS with ONE barrier per K-slab
// + __launch_bounds__(256,4) capping VGPR at 128 (4 waves/SIMD)
//   so the staged prefetch cannot collapse occupancy (round-12 lesson).
// C[M][N] = act(A[M][K] @ Bt[N][K]^T + bias). M,N %128==0, K %16==0.
// ===========================================================================
template<int ACT>   // 0 none, 1 relu, 2 sigmoid
__global__ __launch_bounds__(256, 4)
void k_fgemm(const float* __restrict__ A, int lda,
             const float* __restrict__ Bt, int ldb,
             const float* __restrict__ bias,
             float* __restrict__ C, int ldc, int K)
{
    __shared__ float As[2][16][132];
    __shared__ float Bs[2][16][132];
    const int t = threadIdx.x;
    const int tx = t & 15, ty = t >> 4;
    const long brow = (long)blockIdx.y * 128;
    const long bcol = (long)blockIdx.x * 128;
    const int sr = t >> 1;
    const int kq = (t & 1) * 8;

    f32x2 acc[8][4];
#pragma unroll
    for (int i = 0; i < 8; ++i)
#pragma unroll
        for (int j = 0; j < 4; ++j) acc[i][j] = (f32x2){0.f, 0.f};

    const float* pa = A + (brow + sr) * (long)lda + kq;
    const float* pb = Bt + (bcol + sr) * (long)ldb + kq;

    // prologue: stage slab 0 into buf 0
    {
        const float4 a0 = *(const float4*)(pa);
        const float4 a1 = *(const float4*)(pa + 4);
        const float4 b0 = *(const float4*)(pb);
        const float4 b1 = *(const float4*)(pb + 4);
        As[0][kq + 0][sr] = a0.x; As[0][kq + 1][sr] = a0.y; As[0][kq + 2][sr] = a0.z; As[0][kq + 3][sr] = a0.w;
        As[0][kq + 4][sr] = a1.x; As[0][kq + 5][sr] = a1.y; As[0][kq + 6][sr] = a1.z; As[0][kq + 7][sr] = a1.w;
        Bs[0][kq + 0][sr] = b0.x; Bs[0][kq + 1][sr] = b0.y; Bs[0][kq + 2][sr] = b0.z; Bs[0][kq + 3][sr] = b0.w;
        Bs[0][kq + 4][sr] = b1.x; Bs[0][kq + 5][sr] = b1.y; Bs[0][kq + 6][sr] = b1.z; Bs[0][kq + 7][sr] = b1.w;
    }
    __syncthreads();

    const int nslab = K >> 4;
    for (int it = 0; it < nslab; ++it) {
        const int cur = it & 1, nxt = cur ^ 1;
        float4 na0, na1, nb0, nb1;
        const bool more = (it + 1) < nslab;
        if (more) {                           // prefetch next slab to regs
            const float* qa = pa + (it + 1) * 16;
            const float* qb = pb + (it + 1) * 16;
            na0 = *(const float4*)(qa);
            na1 = *(const float4*)(qa + 4);
            nb0 = *(const float4*)(qb);
            nb1 = *(const float4*)(qb + 4);
        }
#pragma unroll
        for (int kk = 0; kk < 16; ++kk) {
            float av[8], bv[8];
            *(float4*)&av[0] = *(const float4*)&As[cur][kk][ty * 8];
            *(float4*)&av[4] = *(const float4*)&As[cur][kk][ty * 8 + 4];
            *(float4*)&bv[0] = *(const float4*)&Bs[cur][kk][tx * 4];        // 2-way (free)
            *(float4*)&bv[4] = *(const float4*)&Bs[cur][kk][tx * 4 + 64];   // 2-way (free)
#pragma unroll
            for (int i = 0; i < 8; ++i) {
                const f32x2 ai = {av[i], av[i]};
#pragma unroll
                for (int j = 0; j < 4; ++j) {
                    const f32x2 bj = {bv[j * 2], bv[j * 2 + 1]};
                    acc[i][j].x = fmaf(ai.x, bj.x, acc[i][j].x);
                    acc[i][j].y = fmaf(ai.y, bj.y, acc[i][j].y);
                }
            }
        }
        if (more) {                           // write prefetch into other buffer
            As[nxt][kq + 0][sr] = na0.x; As[nxt][kq + 1][sr] = na0.y; As[nxt][kq + 2][sr] = na0.z; As[nxt][kq + 3][sr] = na0.w;
            As[nxt][kq + 4][sr] = na1.x; As[nxt][kq + 5][sr] = na1.y; As[nxt][kq + 6][sr] = na1.z; As[nxt][kq + 7][sr] = na1.w;
            Bs[nxt][kq + 0][sr] = nb0.x; Bs[nxt][kq + 1][sr] = nb0.y; Bs[nxt][kq + 2][sr] = nb0.z; Bs[nxt][kq + 3][sr] = nb0.w;
            Bs[nxt][kq + 4][sr] = nb1.x; Bs[nxt][kq + 5][sr] = nb1.y; Bs[nxt][kq + 6][sr] = nb1.z; Bs[nxt][kq + 7][sr] = nb1.w;
        }
        __syncthreads();                      // single barrier per slab
    }

    // cols: bcol + tx*4 + {0,64} + (j&3)
    float bb[8];
#pragma unroll
    for (int j = 0; j < 8; ++j)
        bb[j] = bias ? bias[bcol + tx * 4 + (j >> 2) * 64 + (j & 3)] : 0.f;
#pragma unroll
    for (int i = 0; i < 8; ++i) {
        float o[8];
#pragma unroll
        for (int j = 0; j < 4; ++j) { o[j * 2] = acc[i][j].x; o[j * 2 + 1] = acc[i][j].y; }
        float r[8];
#pragma unroll
        for (int j = 0; j < 8; ++j) {
            float v = o[j] + bb[j];
            if (ACT == 1) v = fmaxf(v, 0.f);
            if (ACT == 2) v = sigm(v);
            r[j] = v;
        }
        float* cp = C + (brow + ty * 8 + i) * (long)ldc + bcol + tx * 4;
        *(float4*)cp = *(const float4*)&r[0];
        *(float4*)(cp + 64) = *(const float4*)&r[4];
    }
}

// fp32 [K][N] -> fp32 [N][K] transpose (weights -> Bt layout)
__global__ __launch_bounds__(256)
void k_transposeF(const float* __restrict__ W, float* __restrict__ Wt, int K, int N)
{
    __shared__ float tile[32][33];
    const int n0 = blockIdx.x * 32, k0 = blockIdx.y * 32;
    const int tx = threadIdx.x & 31, ty = threadIdx.x >> 5;
#pragma unroll
    for (int r = 0; r < 4; ++r)
        tile[ty + r * 8][tx] = W[(long)(k0 + ty + r * 8) * N + n0 + tx];
    __syncthreads();
#pragma unroll
    for (int r = 0; r < 4; ++r)
        Wt[(long)(n0 + ty + r * 8) * K + k0 + tx] = tile[tx][ty + r * 8];
}

// f32 copy with output leading dim (features -> gcat[:,512:1536])
__global__ void k_copyF(const float* __restrict__ s, float* __restrict__ d, int C, int ldd)
{
    const long idx = ((long)blockIdx.x * 256 + threadIdx.x) * 4;
    const long r = idx / C; const int c = (int)(idx % C);
    *(float4*)(d + r * (long)ldd + c) = *(const float4*)(s + r * (long)C + c);
}

// embedding gather: hcat[row][0:512] = hcat[row][512:1024] = embed_W[tok]
__global__ void k_embedF(const int* __restrict__ at, const float* __restrict__ ew,
                         float* __restrict__ hcat)
{
    const long idx = (long)blockIdx.x * 256 + threadIdx.x;
    const long row = idx >> 6; const int c8 = (int)(idx & 63) * 8;
    const int tok = at[row];
    const float4 v0 = *(const float4*)(ew + (long)tok * 512 + c8);
    const float4 v1 = *(const float4*)(ew + (long)tok * 512 + c8 + 4);
    float* o = hcat + row * 1024 + c8;
    *(float4*)o = v0;           *(float4*)(o + 4) = v1;
    *(float4*)(o + 512) = v0;   *(float4*)(o + 516) = v1;
}

// sparse edge-typed einsum (round-3 proven):
// mout[n*64+i][h] = sum_{e,j: adj[n,e,i,j]!=0} msg[n*64+j][e*512+h]
__global__ __launch_bounds__(256)
void k_einsum_s(const float* __restrict__ adj, const float* __restrict__ msg,
                float* __restrict__ mout)
{
    const int b = blockIdx.x;
    const int n = b >> 6, i = b & 63;
    const int t = threadIdx.x;
    float a0 = 0.f, a1 = 0.f;
#pragma unroll
    for (int e = 0; e < 4; ++e) {
        const float* ar = adj + (((long)n * 4 + e) * 64 + i) * 64;
        const float* me = msg + (long)n * 64 * 2048 + e * 512;
        for (int j = 0; j < 64; ++j) {
            if (ar[j] != 0.f) {
                const float* mr = me + (long)j * 2048;
                a0 += mr[t]; a1 += mr[t + 256];
            }
        }
    }
    mout[(long)b * 512 + t] = a0;
    mout[(long)b * 512 + t + 256] = a1;
}

// GRU elementwise (f32); h kept in hcat[:,0:512]
template<int STEP0>
__global__ __launch_bounds__(256)
void k_gruF(const float* __restrict__ gi, const float* __restrict__ gh,
            const float* __restrict__ bhh, float* __restrict__ hcat)
{
    const long idx = (long)blockIdx.x * 256 + threadIdx.x;
    const long row = idx >> 7; const int c4 = (int)(idx & 127) * 4;
    const float* gir = gi + row * 1536 + c4;
    const float4 xr = *(const float4*)(gir);
    const float4 xz = *(const float4*)(gir + 512);
    const float4 xn = *(const float4*)(gir + 1024);
    float* hp = hcat + row * 1024 + c4;
    const float4 hv = *(const float4*)hp;
    float4 hr, hz, hn;
    if (STEP0) {
        hr = *(const float4*)(bhh + c4);
        hz = *(const float4*)(bhh + 512 + c4);
        hn = *(const float4*)(bhh + 1024 + c4);
    } else {
        const float* ghr = gh + row * 1536 + c4;
        hr = *(const float4*)(ghr);
        hz = *(const float4*)(ghr + 512);
        hn = *(const float4*)(ghr + 1024);
    }
    const float xra[4] = {xr.x, xr.y, xr.z, xr.w};
    const float xza[4] = {xz.x, xz.y, xz.z, xz.w};
    const float xna[4] = {xn.x, xn.y, xn.z, xn.w};
    const float hra[4] = {hr.x, hr.y, hr.z, hr.w};
    const float hza[4] = {hz.x, hz.y, hz.z, hz.w};
    const float hna[4] = {hn.x, hn.y, hn.z, hn.w};
    const float hva[4] = {hv.x, hv.y, hv.z, hv.w};
    float o[4];
#pragma unroll
    for (int k = 0; k < 4; ++k) {
        const float hprev = STEP0 ? 0.f : hva[k];
        const float r = sigm(xra[k] + hra[k]);
        const float z = sigm(xza[k] + hza[k]);
        const float nn = tanh_fast(xna[k] + r * hna[k]);
        o[k] = (1.f - z) * nn + z * hprev;
    }
    float4 ov; ov.x = o[0]; ov.y = o[1]; ov.z = o[2]; ov.w = o[3];
    *(float4*)hp = ov;
}

// readout: g[n,h] = (65/128) * sum_a gate[n*64+a][h]*jj[n*64+a][h]
__global__ __launch_bounds__(256)
void k_readout(const float* __restrict__ gate, const float* __restrict__ jj, float* __restrict__ g)
{
    const int n = blockIdx.x, t = threadIdx.x;
    float a0 = 0.f, a1 = 0.f;
    for (int a = 0; a < 64; ++a) {
        const long base = ((long)n * 64 + a) * 512;
        a0 += gate[base + t] * jj[base + t];
        a1 += gate[base + t + 256] * jj[base + t + 256];
    }
    g[(long)n * 512 + t]       = a0 * (65.f / 128.f);
    g[(long)n * 512 + t + 256] = a1 * (65.f / 128.f);
}

// attention fusion over the two views -> fused f32 [1024][512]
__global__ __launch_bounds__(128)
void k_att(const float* __restrict__ g, const float* __restrict__ emb,
           const float* __restrict__ W1, const float* __restrict__ bias1,
           const float* __restrict__ W2, float* __restrict__ fused)
{
    __shared__ float v[512];
    __shared__ float red[128];
    __shared__ float sres[2];
    const int n = blockIdx.x, t = threadIdx.x;
    for (int view = 0; view < 2; ++view) {
        const float* src = (view ? emb : g) + (long)n * 512;
        for (int k = t; k < 512; k += 128) v[k] = src[k];
        __syncthreads();
        float acc = bias1[t];
        for (int k = 0; k < 512; ++k) acc += v[k] * W1[k * 128 + t];
        red[t] = tanh_fast(acc) * W2[t];
        __syncthreads();
        if (t == 0) { float s = 0.f; for (int i = 0; i < 128; ++i) s += red[i]; sres[view] = s; }
        __syncthreads();
    }
    const float b0 = 1.f / (1.f + __expf(sres[1] - sres[0]));
    const float b1v = 1.f - b0;
    for (int k = t; k < 512; k += 128) {
        fused[(long)n * 512 + k] = b0 * g[(long)n * 512 + k] + b1v * emb[(long)n * 512 + k];
    }
}

// ===========================================================================
// host side
// ===========================================================================
static void sgemm(hipStream_t st, const float* A, int lda, const float* B, int ldb,
                  const float* bias, float* C, int ldc, int M, int N, int K, int act)
{
    dim3 g(N / 128, M / 128), b(256);
    if (act == 0)      k_fgemm<0><<<g, b, 0, st>>>(A, lda, B, ldb, bias, C, ldc, K);
    else if (act == 1) k_fgemm<1><<<g, b, 0, st>>>(A, lda, B, ldb, bias, C, ldc, K);
    else               k_fgemm<2><<<g, b, 0, st>>>(A, lda, B, ldb, bias, C, ldc, K);
}

extern "C" void kernel_launch(void* const* d_in, const int* in_sizes, int n_in,
                              void* d_out, int out_size, void* d_ws, size_t ws_size,
                              hipStream_t stream)
{
    const int*   atom = (const int*)  d_in[0];
    const float* adj  = (const float*)d_in[1];
    const float* feat = (const float*)d_in[2];
    const float* adjn = (const float*)d_in[3];
    const float* embW = (const float*)d_in[4];
    const float* msgW = (const float*)d_in[5];
    const float* msgb = (const float*)d_in[6];
    const float* Wih  = (const float*)d_in[7];
    const float* Whh  = (const float*)d_in[8];
    const float* bih  = (const float*)d_in[9];
    const float* bhh  = (const float*)d_in[10];
    const float* iW   = (const float*)d_in[11];
    const float* ib   = (const float*)d_in[12];
    const float* jW   = (const float*)d_in[13];
    const float* jb   = (const float*)d_in[14];
    const float* gc1  = (const float*)d_in[15];
    const float* gc2  = (const float*)d_in[16];
    const float* gc3  = (const float*)d_in[17];
    const float* thW  = (const float*)d_in[18];
    const float* thb  = (const float*)d_in[19];
    const float* th1W = (const float*)d_in[20];
    const float* th1b = (const float*)d_in[21];
    const float* th2W = (const float*)d_in[22];
    const float* th2b = (const float*)d_in[23];
    const float* aW1  = (const float*)d_in[24];
    const float* ab1  = (const float*)d_in[25];
    const float* aW2  = (const float*)d_in[26];

    // ---- fixed workspace region (identical to passing round 13) ----
    constexpr size_t O_WTMSG = 0;
    constexpr size_t O_WTWIH = O_WTMSG + (size_t)3 * 2048 * 512 * 4;
    constexpr size_t O_WTWHH = O_WTWIH + (size_t)1536 * 512 * 4;
    constexpr size_t O_WTIW  = O_WTWHH + (size_t)1536 * 512 * 4;
    constexpr size_t O_WTJW  = O_WTIW  + (size_t)512 * 1024 * 4;
    constexpr size_t O_WTGC1 = O_WTJW  + (size_t)512 * 512 * 4;
    constexpr size_t O_WTGC2 = O_WTGC1 + (size_t)512 * 1024 * 4;
    constexpr size_t O_WTGC3 = O_WTGC2 + (size_t)512 * 512 * 4;
    constexpr size_t O_WTTH  = O_WTGC3 + (size_t)512 * 512 * 4;
    constexpr size_t O_WTTH1 = O_WTTH  + (size_t)512 * 1536 * 4;
    constexpr size_t O_WTTH2 = O_WTTH1 + (size_t)512 * 1536 * 4;
    constexpr size_t O_GCAT  = O_WTTH2 + (size_t)512 * 1536 * 4;
    constexpr size_t O_PT    = O_GCAT  + (size_t)1024 * 1536 * 4;
    constexpr size_t O_H1    = O_PT    + (size_t)512 * 1024 * 4;
    constexpr size_t O_H2    = O_H1    + (size_t)1024 * 512 * 4;
    constexpr size_t O_EMBF  = O_H2    + (size_t)1024 * 512 * 4;
    constexpr size_t O_GF    = O_EMBF  + (size_t)1024 * 512 * 4;
    constexpr size_t O_FUSED = O_GF    + (size_t)1024 * 512 * 4;
    constexpr size_t O_CHUNK = O_FUSED + (size_t)1024 * 512 * 4;

    // per-atom-row chunk bytes: hcat 4096 + gh 6144 + magg 2048 + msg 8192 = 20480
    int C = 1024;
    while (C > 2 && O_CHUNK + (size_t)64 * C * 20480 > ws_size) C >>= 1;
    if (O_CHUNK + (size_t)64 * C * 20480 > ws_size) return;
    const int R = C * 64;
    const int nchunks = 1024 / C;

    uint8_t* wsb = (uint8_t*)d_ws;
    float* wtMsg = (float*)(wsb + O_WTMSG);
    float* wtWih = (float*)(wsb + O_WTWIH);
    float* wtWhh = (float*)(wsb + O_WTWHH);
    float* wtIw  = (float*)(wsb + O_WTIW);
    float* wtJw  = (float*)(wsb + O_WTJW);
    float* wtGc1 = (float*)(wsb + O_WTGC1);
    float* wtGc2 = (float*)(wsb + O_WTGC2);
    float* wtGc3 = (float*)(wsb + O_WTGC3);
    float* wtTh  = (float*)(wsb + O_WTTH);
    float* wtTh1 = (float*)(wsb + O_WTTH1);
    float* wtTh2 = (float*)(wsb + O_WTTH2);
    float* gcatF = (float*)(wsb + O_GCAT);
    float* ptF   = (float*)(wsb + O_PT);
    float* h1F   = (float*)(wsb + O_H1);
    float* h2F   = (float*)(wsb + O_H2);
    float* embF  = (float*)(wsb + O_EMBF);
    float* gF    = (float*)(wsb + O_GF);
    float* fusedF= (float*)(wsb + O_FUSED);
    uint8_t* cr = wsb + O_CHUNK;
    float* hcatF = (float*)(cr);
    float* ghF   = (float*)(cr + (size_t)R * 4096);
    float* maggF = (float*)(cr + (size_t)R * 10240);
    float* msgF  = (float*)(cr + (size_t)R * 12288);
    float* giF   = msgF;                                   // alias: msg dead when gi written
    float* gateF = msgF;                                   // alias: post-GRU phase
    float* jjF   = msgF + (size_t)R * 512;

    // ---- weight prep (f32 transposed to Bt [N][K]) — once ----
    for (int s = 0; s < 3; ++s)
        k_transposeF<<<dim3(64, 16), 256, 0, stream>>>(msgW + (size_t)s * 512 * 2048,
                                                       wtMsg + (size_t)s * 2048 * 512, 512, 2048);
    k_transposeF<<<dim3(48, 16), 256, 0, stream>>>(Wih, wtWih, 512, 1536);
    k_transposeF<<<dim3(48, 16), 256, 0, stream>>>(Whh, wtWhh, 512, 1536);
    k_transposeF<<<dim3(16, 32), 256, 0, stream>>>(iW,  wtIw, 1024, 512);
    k_transposeF<<<dim3(16, 16), 256, 0, stream>>>(jW,  wtJw,  512, 512);
    k_transposeF<<<dim3(16, 32), 256, 0, stream>>>(gc1, wtGc1, 1024, 512);
    k_transposeF<<<dim3(16, 16), 256, 0, stream>>>(gc2, wtGc2, 512, 512);
    k_transposeF<<<dim3(16, 16), 256, 0, stream>>>(gc3, wtGc3, 512, 512);
    k_transposeF<<<dim3(16, 48), 256, 0, stream>>>(thW,  wtTh,  1536, 512);
    k_transposeF<<<dim3(16, 48), 256, 0, stream>>>(th1W, wtTh1, 1536, 512);
    k_transposeF<<<dim3(16, 48), 256, 0, stream>>>(th2W, wtTh2, 1536, 512);
    k_copyF<<<1024, 256, 0, stream>>>(feat, gcatF + 512, 1024, 1536);

    // ---- GGNN + readout, chunked over molecules ----
    for (int c = 0; c < nchunks; ++c) {
        const size_t arow0 = (size_t)c * R;
        k_embedF<<<R / 4, 256, 0, stream>>>(atom + arow0, embW, hcatF);
        for (int s = 0; s < 3; ++s) {
            sgemm(stream, hcatF, 1024, wtMsg + (size_t)s * 2048 * 512, 512,
                  msgb + (size_t)s * 2048, msgF, 2048, R, 2048, 512, 0);
            k_einsum_s<<<R, 256, 0, stream>>>(adj + (size_t)c * C * 4 * 64 * 64, msgF, maggF);
            sgemm(stream, maggF, 512, wtWih, 512, bih, giF, 1536, R, 1536, 512, 0);
            if (s > 0)
                sgemm(stream, hcatF, 1024, wtWhh, 512, bhh, ghF, 1536, R, 1536, 512, 0);
            if (s == 0) k_gruF<1><<<R / 2, 256, 0, stream>>>(giF, nullptr, bhh, hcatF);
            else        k_gruF<0><<<R / 2, 256, 0, stream>>>(giF, ghF, bhh, hcatF);
        }
        sgemm(stream, hcatF, 1024, wtIw, 1024, ib, gateF, 512, R, 512, 1024, 2);
        sgemm(stream, hcatF, 1024, wtJw,  512, jb, jjF,   512, R, 512,  512, 0);
        k_readout<<<C, 256, 0, stream>>>(gateF, jjF, gF + (size_t)c * C * 512);
    }

    // ---- GCN drug encoder ----
    sgemm(stream, wtGc1, 1024, feat, 1024, nullptr, ptF, 1024, 512, 1024, 1024, 0);
    sgemm(stream, adjn, 1024, ptF, 1024, nullptr, gcatF, 1536, 1024, 512, 1024, 0);
    sgemm(stream, gcatF, 1536, wtTh, 1536, thb, h1F, 512, 1024, 512, 1536, 1);
    sgemm(stream, wtGc2, 512, h1F, 512, nullptr, ptF, 1024, 512, 1024, 512, 0);
    sgemm(stream, adjn, 1024, ptF, 1024, nullptr, gcatF, 1536, 1024, 512, 1024, 0);
    sgemm(stream, gcatF, 1536, wtTh1, 1536, th1b, h2F, 512, 1024, 512, 1536, 1);
    sgemm(stream, wtGc3, 512, h2F, 512, nullptr, ptF, 1024, 512, 1024, 512, 0);
    sgemm(stream, adjn, 1024, ptF, 1024, nullptr, gcatF, 1536, 1024, 512, 1024, 0);
    sgemm(stream, gcatF, 1536, wtTh2, 1536, th2b, embF, 512, 1024, 512, 1536, 1);

    // ---- attention fusion + inner-product decoder ----
    k_att<<<1024, 128, 0, stream>>>(gF, embF, aW1, ab1, aW2, fusedF);
    sgemm(stream, fusedF, 512, fusedF, 512, nullptr, (float*)d_out, 1024, 1024, 1024, 512, 2);
}

// Round 15
// 16861.325 us; speedup vs baseline: 12.8084x; 12.8084x over previous
//
#include <hip/hip_runtime.h>
#include <stdint.h>

#define DEV __device__ __forceinline__

typedef __attribute__((ext_vector_type(2))) float f32x2;

DEV float sigm(float x) { return 1.f / (1.f + __expf(-x)); }
DEV float tanh_fast(float x) {
    float e = __expf(-2.f * fabsf(x));
    float t = (1.f - e) / (1.f + e);
    return x < 0.f ? -t : t;
}

// ===========================================================================
// f32 GEMM engine (round-13 proven best: 16,859 us total, 80 TF/dispatch):
// single-buffered LDS, 128x128 tile, 8x8/thread, conflict-free B mapping
// (cols {4tx+r, 64+4tx+r} -> 2-way LDS aliasing = free per m136).
// Double-buffer variants REJECTED by measurement: r12 (184 VGPR -> 11.6%
// occupancy), r14 (launch_bounds cap -> scratch spill, 4.6GB fetch/dispatch).
// C[M][N] = act(A[M][K] @ Bt[N][K]^T + bias). M,N %128==0, K %16==0.
// ===========================================================================
template<int ACT>   // 0 none, 1 relu, 2 sigmoid
__global__ __launch_bounds__(256)
void k_fgemm(const float* __restrict__ A, int lda,
             const float* __restrict__ Bt, int ldb,
             const float* __restrict__ bias,
             float* __restrict__ C, int ldc, int K)
{
    __shared__ float As[16][132];
    __shared__ float Bs[16][132];
    const int t = threadIdx.x;
    const int tx = t & 15, ty = t >> 4;
    const long brow = (long)blockIdx.y * 128;
    const long bcol = (long)blockIdx.x * 128;
    const int sr = t >> 1;
    const int kq = (t & 1) * 8;

    f32x2 acc[8][4];
#pragma unroll
    for (int i = 0; i < 8; ++i)
#pragma unroll
        for (int j = 0; j < 4; ++j) acc[i][j] = (f32x2){0.f, 0.f};

    for (int kt = 0; kt < K; kt += 16) {
        const float4 a0 = *(const float4*)(A  + (brow + sr) * (long)lda + kt + kq);
        const float4 a1 = *(const float4*)(A  + (brow + sr) * (long)lda + kt + kq + 4);
        const float4 b0 = *(const float4*)(Bt + (bcol + sr) * (long)ldb + kt + kq);
        const float4 b1 = *(const float4*)(Bt + (bcol + sr) * (long)ldb + kt + kq + 4);
        As[kq + 0][sr] = a0.x; As[kq + 1][sr] = a0.y; As[kq + 2][sr] = a0.z; As[kq + 3][sr] = a0.w;
        As[kq + 4][sr] = a1.x; As[kq + 5][sr] = a1.y; As[kq + 6][sr] = a1.z; As[kq + 7][sr] = a1.w;
        Bs[kq + 0][sr] = b0.x; Bs[kq + 1][sr] = b0.y; Bs[kq + 2][sr] = b0.z; Bs[kq + 3][sr] = b0.w;
        Bs[kq + 4][sr] = b1.x; Bs[kq + 5][sr] = b1.y; Bs[kq + 6][sr] = b1.z; Bs[kq + 7][sr] = b1.w;
        __syncthreads();
#pragma unroll
        for (int kk = 0; kk < 16; ++kk) {
            float av[8], bv[8];
            *(float4*)&av[0] = *(const float4*)&As[kk][ty * 8];
            *(float4*)&av[4] = *(const float4*)&As[kk][ty * 8 + 4];
            *(float4*)&bv[0] = *(const float4*)&Bs[kk][tx * 4];        // 2-way
            *(float4*)&bv[4] = *(const float4*)&Bs[kk][tx * 4 + 64];   // 2-way
#pragma unroll
            for (int i = 0; i < 8; ++i) {
                const f32x2 ai = {av[i], av[i]};
#pragma unroll
                for (int j = 0; j < 4; ++j) {
                    const f32x2 bj = {bv[j * 2], bv[j * 2 + 1]};
                    acc[i][j].x = fmaf(ai.x, bj.x, acc[i][j].x);
                    acc[i][j].y = fmaf(ai.y, bj.y, acc[i][j].y);
                }
            }
        }
        __syncthreads();
    }

    // cols: bcol + tx*4 + {0,64} + (j&3)
    float bb[8];
#pragma unroll
    for (int j = 0; j < 8; ++j)
        bb[j] = bias ? bias[bcol + tx * 4 + (j >> 2) * 64 + (j & 3)] : 0.f;
#pragma unroll
    for (int i = 0; i < 8; ++i) {
        float o[8];
#pragma unroll
        for (int j = 0; j < 4; ++j) { o[j * 2] = acc[i][j].x; o[j * 2 + 1] = acc[i][j].y; }
        float r[8];
#pragma unroll
        for (int j = 0; j < 8; ++j) {
            float v = o[j] + bb[j];
            if (ACT == 1) v = fmaxf(v, 0.f);
            if (ACT == 2) v = sigm(v);
            r[j] = v;
        }
        float* cp = C + (brow + ty * 8 + i) * (long)ldc + bcol + tx * 4;
        *(float4*)cp = *(const float4*)&r[0];
        *(float4*)(cp + 64) = *(const float4*)&r[4];
    }
}

// fp32 [K][N] -> fp32 [N][K] transpose (weights -> Bt layout)
__global__ __launch_bounds__(256)
void k_transposeF(const float* __restrict__ W, float* __restrict__ Wt, int K, int N)
{
    __shared__ float tile[32][33];
    const int n0 = blockIdx.x * 32, k0 = blockIdx.y * 32;
    const int tx = threadIdx.x & 31, ty = threadIdx.x >> 5;
#pragma unroll
    for (int r = 0; r < 4; ++r)
        tile[ty + r * 8][tx] = W[(long)(k0 + ty + r * 8) * N + n0 + tx];
    __syncthreads();
#pragma unroll
    for (int r = 0; r < 4; ++r)
        Wt[(long)(n0 + ty + r * 8) * K + k0 + tx] = tile[tx][ty + r * 8];
}

// f32 copy with output leading dim (features -> gcat[:,512:1536])
__global__ void k_copyF(const float* __restrict__ s, float* __restrict__ d, int C, int ldd)
{
    const long idx = ((long)blockIdx.x * 256 + threadIdx.x) * 4;
    const long r = idx / C; const int c = (int)(idx % C);
    *(float4*)(d + r * (long)ldd + c) = *(const float4*)(s + r * (long)C + c);
}

// embedding gather: hcat[row][0:512] = hcat[row][512:1024] = embed_W[tok]
__global__ void k_embedF(const int* __restrict__ at, const float* __restrict__ ew,
                         float* __restrict__ hcat)
{
    const long idx = (long)blockIdx.x * 256 + threadIdx.x;
    const long row = idx >> 6; const int c8 = (int)(idx & 63) * 8;
    const int tok = at[row];
    const float4 v0 = *(const float4*)(ew + (long)tok * 512 + c8);
    const float4 v1 = *(const float4*)(ew + (long)tok * 512 + c8 + 4);
    float* o = hcat + row * 1024 + c8;
    *(float4*)o = v0;           *(float4*)(o + 4) = v1;
    *(float4*)(o + 512) = v0;   *(float4*)(o + 516) = v1;
}

// sparse edge-typed einsum (round-3 proven):
// mout[n*64+i][h] = sum_{e,j: adj[n,e,i,j]!=0} msg[n*64+j][e*512+h]
__global__ __launch_bounds__(256)
void k_einsum_s(const float* __restrict__ adj, const float* __restrict__ msg,
                float* __restrict__ mout)
{
    const int b = blockIdx.x;
    const int n = b >> 6, i = b & 63;
    const int t = threadIdx.x;
    float a0 = 0.f, a1 = 0.f;
#pragma unroll
    for (int e = 0; e < 4; ++e) {
        const float* ar = adj + (((long)n * 4 + e) * 64 + i) * 64;
        const float* me = msg + (long)n * 64 * 2048 + e * 512;
        for (int j = 0; j < 64; ++j) {
            if (ar[j] != 0.f) {
                const float* mr = me + (long)j * 2048;
                a0 += mr[t]; a1 += mr[t + 256];
            }
        }
    }
    mout[(long)b * 512 + t] = a0;
    mout[(long)b * 512 + t + 256] = a1;
}

// GRU elementwise (f32); h kept in hcat[:,0:512]
template<int STEP0>
__global__ __launch_bounds__(256)
void k_gruF(const float* __restrict__ gi, const float* __restrict__ gh,
            const float* __restrict__ bhh, float* __restrict__ hcat)
{
    const long idx = (long)blockIdx.x * 256 + threadIdx.x;
    const long row = idx >> 7; const int c4 = (int)(idx & 127) * 4;
    const float* gir = gi + row * 1536 + c4;
    const float4 xr = *(const float4*)(gir);
    const float4 xz = *(const float4*)(gir + 512);
    const float4 xn = *(const float4*)(gir + 1024);
    float* hp = hcat + row * 1024 + c4;
    const float4 hv = *(const float4*)hp;
    float4 hr, hz, hn;
    if (STEP0) {
        hr = *(const float4*)(bhh + c4);
        hz = *(const float4*)(bhh + 512 + c4);
        hn = *(const float4*)(bhh + 1024 + c4);
    } else {
        const float* ghr = gh + row * 1536 + c4;
        hr = *(const float4*)(ghr);
        hz = *(const float4*)(ghr + 512);
        hn = *(const float4*)(ghr + 1024);
    }
    const float xra[4] = {xr.x, xr.y, xr.z, xr.w};
    const float xza[4] = {xz.x, xz.y, xz.z, xz.w};
    const float xna[4] = {xn.x, xn.y, xn.z, xn.w};
    const float hra[4] = {hr.x, hr.y, hr.z, hr.w};
    const float hza[4] = {hz.x, hz.y, hz.z, hz.w};
    const float hna[4] = {hn.x, hn.y, hn.z, hn.w};
    const float hva[4] = {hv.x, hv.y, hv.z, hv.w};
    float o[4];
#pragma unroll
    for (int k = 0; k < 4; ++k) {
        const float hprev = STEP0 ? 0.f : hva[k];
        const float r = sigm(xra[k] + hra[k]);
        const float z = sigm(xza[k] + hza[k]);
        const float nn = tanh_fast(xna[k] + r * hna[k]);
        o[k] = (1.f - z) * nn + z * hprev;
    }
    float4 ov; ov.x = o[0]; ov.y = o[1]; ov.z = o[2]; ov.w = o[3];
    *(float4*)hp = ov;
}

// readout: g[n,h] = (65/128) * sum_a gate[n*64+a][h]*jj[n*64+a][h]
__global__ __launch_bounds__(256)
void k_readout(const float* __restrict__ gate, const float* __restrict__ jj, float* __restrict__ g)
{
    const int n = blockIdx.x, t = threadIdx.x;
    float a0 = 0.f, a1 = 0.f;
    for (int a = 0; a < 64; ++a) {
        const long base = ((long)n * 64 + a) * 512;
        a0 += gate[base + t] * jj[base + t];
        a1 += gate[base + t + 256] * jj[base + t + 256];
    }
    g[(long)n * 512 + t]       = a0 * (65.f / 128.f);
    g[(long)n * 512 + t + 256] = a1 * (65.f / 128.f);
}

// attention fusion over the two views -> fused f32 [1024][512]
__global__ __launch_bounds__(128)
void k_att(const float* __restrict__ g, const float* __restrict__ emb,
           const float* __restrict__ W1, const float* __restrict__ bias1,
           const float* __restrict__ W2, float* __restrict__ fused)
{
    __shared__ float v[512];
    __shared__ float red[128];
    __shared__ float sres[2];
    const int n = blockIdx.x, t = threadIdx.x;
    for (int view = 0; view < 2; ++view) {
        const float* src = (view ? emb : g) + (long)n * 512;
        for (int k = t; k < 512; k += 128) v[k] = src[k];
        __syncthreads();
        float acc = bias1[t];
        for (int k = 0; k < 512; ++k) acc += v[k] * W1[k * 128 + t];
        red[t] = tanh_fast(acc) * W2[t];
        __syncthreads();
        if (t == 0) { float s = 0.f; for (int i = 0; i < 128; ++i) s += red[i]; sres[view] = s; }
        __syncthreads();
    }
    const float b0 = 1.f / (1.f + __expf(sres[1] - sres[0]));
    const float b1v = 1.f - b0;
    for (int k = t; k < 512; k += 128) {
        fused[(long)n * 512 + k] = b0 * g[(long)n * 512 + k] + b1v * emb[(long)n * 512 + k];
    }
}

// ===========================================================================
// host side
// ===========================================================================
static void sgemm(hipStream_t st, const float* A, int lda, const float* B, int ldb,
                  const float* bias, float* C, int ldc, int M, int N, int K, int act)
{
    dim3 g(N / 128, M / 128), b(256);
    if (act == 0)      k_fgemm<0><<<g, b, 0, st>>>(A, lda, B, ldb, bias, C, ldc, K);
    else if (act == 1) k_fgemm<1><<<g, b, 0, st>>>(A, lda, B, ldb, bias, C, ldc, K);
    else               k_fgemm<2><<<g, b, 0, st>>>(A, lda, B, ldb, bias, C, ldc, K);
}

extern "C" void kernel_launch(void* const* d_in, const int* in_sizes, int n_in,
                              void* d_out, int out_size, void* d_ws, size_t ws_size,
                              hipStream_t stream)
{
    const int*   atom = (const int*)  d_in[0];
    const float* adj  = (const float*)d_in[1];
    const float* feat = (const float*)d_in[2];
    const float* adjn = (const float*)d_in[3];
    const float* embW = (const float*)d_in[4];
    const float* msgW = (const float*)d_in[5];
    const float* msgb = (const float*)d_in[6];
    const float* Wih  = (const float*)d_in[7];
    const float* Whh  = (const float*)d_in[8];
    const float* bih  = (const float*)d_in[9];
    const float* bhh  = (const float*)d_in[10];
    const float* iW   = (const float*)d_in[11];
    const float* ib   = (const float*)d_in[12];
    const float* jW   = (const float*)d_in[13];
    const float* jb   = (const float*)d_in[14];
    const float* gc1  = (const float*)d_in[15];
    const float* gc2  = (const float*)d_in[16];
    const float* gc3  = (const float*)d_in[17];
    const float* thW  = (const float*)d_in[18];
    const float* thb  = (const float*)d_in[19];
    const float* th1W = (const float*)d_in[20];
    const float* th1b = (const float*)d_in[21];
    const float* th2W = (const float*)d_in[22];
    const float* th2b = (const float*)d_in[23];
    const float* aW1  = (const float*)d_in[24];
    const float* ab1  = (const float*)d_in[25];
    const float* aW2  = (const float*)d_in[26];

    // ---- fixed workspace region (identical to passing round 13) ----
    constexpr size_t O_WTMSG = 0;
    constexpr size_t O_WTWIH = O_WTMSG + (size_t)3 * 2048 * 512 * 4;
    constexpr size_t O_WTWHH = O_WTWIH + (size_t)1536 * 512 * 4;
    constexpr size_t O_WTIW  = O_WTWHH + (size_t)1536 * 512 * 4;
    constexpr size_t O_WTJW  = O_WTIW  + (size_t)512 * 1024 * 4;
    constexpr size_t O_WTGC1 = O_WTJW  + (size_t)512 * 512 * 4;
    constexpr size_t O_WTGC2 = O_WTGC1 + (size_t)512 * 1024 * 4;
    constexpr size_t O_WTGC3 = O_WTGC2 + (size_t)512 * 512 * 4;
    constexpr size_t O_WTTH  = O_WTGC3 + (size_t)512 * 512 * 4;
    constexpr size_t O_WTTH1 = O_WTTH  + (size_t)512 * 1536 * 4;
    constexpr size_t O_WTTH2 = O_WTTH1 + (size_t)512 * 1536 * 4;
    constexpr size_t O_GCAT  = O_WTTH2 + (size_t)512 * 1536 * 4;
    constexpr size_t O_PT    = O_GCAT  + (size_t)1024 * 1536 * 4;
    constexpr size_t O_H1    = O_PT    + (size_t)512 * 1024 * 4;
    constexpr size_t O_H2    = O_H1    + (size_t)1024 * 512 * 4;
    constexpr size_t O_EMBF  = O_H2    + (size_t)1024 * 512 * 4;
    constexpr size_t O_GF    = O_EMBF  + (size_t)1024 * 512 * 4;
    constexpr size_t O_FUSED = O_GF    + (size_t)1024 * 512 * 4;
    constexpr size_t O_CHUNK = O_FUSED + (size_t)1024 * 512 * 4;

    // per-atom-row chunk bytes: hcat 4096 + gh 6144 + magg 2048 + msg 8192 = 20480
    int C = 1024;
    while (C > 2 && O_CHUNK + (size_t)64 * C * 20480 > ws_size) C >>= 1;
    if (O_CHUNK + (size_t)64 * C * 20480 > ws_size) return;
    const int R = C * 64;
    const int nchunks = 1024 / C;

    uint8_t* wsb = (uint8_t*)d_ws;
    float* wtMsg = (float*)(wsb + O_WTMSG);
    float* wtWih = (float*)(wsb + O_WTWIH);
    float* wtWhh = (float*)(wsb + O_WTWHH);
    float* wtIw  = (float*)(wsb + O_WTIW);
    float* wtJw  = (float*)(wsb + O_WTJW);
    float* wtGc1 = (float*)(wsb + O_WTGC1);
    float* wtGc2 = (float*)(wsb + O_WTGC2);
    float* wtGc3 = (float*)(wsb + O_WTGC3);
    float* wtTh  = (float*)(wsb + O_WTTH);
    float* wtTh1 = (float*)(wsb + O_WTTH1);
    float* wtTh2 = (float*)(wsb + O_WTTH2);
    float* gcatF = (float*)(wsb + O_GCAT);
    float* ptF   = (float*)(wsb + O_PT);
    float* h1F   = (float*)(wsb + O_H1);
    float* h2F   = (float*)(wsb + O_H2);
    float* embF  = (float*)(wsb + O_EMBF);
    float* gF    = (float*)(wsb + O_GF);
    float* fusedF= (float*)(wsb + O_FUSED);
    uint8_t* cr = wsb + O_CHUNK;
    float* hcatF = (float*)(cr);
    float* ghF   = (float*)(cr + (size_t)R * 4096);
    float* maggF = (float*)(cr + (size_t)R * 10240);
    float* msgF  = (float*)(cr + (size_t)R * 12288);
    float* giF   = msgF;                                   // alias: msg dead when gi written
    float* gateF = msgF;                                   // alias: post-GRU phase
    float* jjF   = msgF + (size_t)R * 512;

    // ---- weight prep (f32 transposed to Bt [N][K]) — once ----
    for (int s = 0; s < 3; ++s)
        k_transposeF<<<dim3(64, 16), 256, 0, stream>>>(msgW + (size_t)s * 512 * 2048,
                                                       wtMsg + (size_t)s * 2048 * 512, 512, 2048);
    k_transposeF<<<dim3(48, 16), 256, 0, stream>>>(Wih, wtWih, 512, 1536);
    k_transposeF<<<dim3(48, 16), 256, 0, stream>>>(Whh, wtWhh, 512, 1536);
    k_transposeF<<<dim3(16, 32), 256, 0, stream>>>(iW,  wtIw, 1024, 512);
    k_transposeF<<<dim3(16, 16), 256, 0, stream>>>(jW,  wtJw,  512, 512);
    k_transposeF<<<dim3(16, 32), 256, 0, stream>>>(gc1, wtGc1, 1024, 512);
    k_transposeF<<<dim3(16, 16), 256, 0, stream>>>(gc2, wtGc2, 512, 512);
    k_transposeF<<<dim3(16, 16), 256, 0, stream>>>(gc3, wtGc3, 512, 512);
    k_transposeF<<<dim3(16, 48), 256, 0, stream>>>(thW,  wtTh,  1536, 512);
    k_transposeF<<<dim3(16, 48), 256, 0, stream>>>(th1W, wtTh1, 1536, 512);
    k_transposeF<<<dim3(16, 48), 256, 0, stream>>>(th2W, wtTh2, 1536, 512);
    k_copyF<<<1024, 256, 0, stream>>>(feat, gcatF + 512, 1024, 1536);

    // ---- GGNN + readout, chunked over molecules ----
    for (int c = 0; c < nchunks; ++c) {
        const size_t arow0 = (size_t)c * R;
        k_embedF<<<R / 4, 256, 0, stream>>>(atom + arow0, embW, hcatF);
        for (int s = 0; s < 3; ++s) {
            sgemm(stream, hcatF, 1024, wtMsg + (size_t)s * 2048 * 512, 512,
                  msgb + (size_t)s * 2048, msgF, 2048, R, 2048, 512, 0);
            k_einsum_s<<<R, 256, 0, stream>>>(adj + (size_t)c * C * 4 * 64 * 64, msgF, maggF);
            sgemm(stream, maggF, 512, wtWih, 512, bih, giF, 1536, R, 1536, 512, 0);
            if (s > 0)
                sgemm(stream, hcatF, 1024, wtWhh, 512, bhh, ghF, 1536, R, 1536, 512, 0);
            if (s == 0) k_gruF<1><<<R / 2, 256, 0, stream>>>(giF, nullptr, bhh, hcatF);
            else        k_gruF<0><<<R / 2, 256, 0, stream>>>(giF, ghF, bhh, hcatF);
        }
        sgemm(stream, hcatF, 1024, wtIw, 1024, ib, gateF, 512, R, 512, 1024, 2);
        sgemm(stream, hcatF, 1024, wtJw,  512, jb, jjF,   512, R, 512,  512, 0);
        k_readout<<<C, 256, 0, stream>>>(gateF, jjF, gF + (size_t)c * C * 512);
    }

    // ---- GCN drug encoder ----
    sgemm(stream, wtGc1, 1024, feat, 1024, nullptr, ptF, 1024, 512, 1024, 1024, 0);
    sgemm(stream, adjn, 1024, ptF, 1024, nullptr, gcatF, 1536, 1024, 512, 1024, 0);
    sgemm(stream, gcatF, 1536, wtTh, 1536, thb, h1F, 512, 1024, 512, 1536, 1);
    sgemm(stream, wtGc2, 512, h1F, 512, nullptr, ptF, 1024, 512, 1024, 512, 0);
    sgemm(stream, adjn, 1024, ptF, 1024, nullptr, gcatF, 1536, 1024, 512, 1024, 0);
    sgemm(stream, gcatF, 1536, wtTh1, 1536, th1b, h2F, 512, 1024, 512, 1536, 1);
    sgemm(stream, wtGc3, 512, h2F, 512, nullptr, ptF, 1024, 512, 1024, 512, 0);
    sgemm(stream, adjn, 1024, ptF, 1024, nullptr, gcatF, 1536, 1024, 512, 1024, 0);
    sgemm(stream, gcatF, 1536, wtTh2, 1536, th2b, embF, 512, 1024, 512, 1536, 1);

    // ---- attention fusion + inner-product decoder ----
    k_att<<<1024, 128, 0, stream>>>(gF, embF, aW1, ab1, aW2, fusedF);
    sgemm(stream, fusedF, 512, fusedF, 512, nullptr, (float*)d_out, 1024, 1024, 1024, 512, 2);
}

// Round 16
// 16661.224 us; speedup vs baseline: 12.9622x; 1.0120x over previous
//
#include <hip/hip_runtime.h>
#include <stdint.h>

#define DEV __device__ __forceinline__

typedef __attribute__((ext_vector_type(2))) float f32x2;

DEV float sigm(float x) { return 1.f / (1.f + __expf(-x)); }
DEV float tanh_fast(float x) {
    float e = __expf(-2.f * fabsf(x));
    float t = (1.f - e) / (1.f + e);
    return x < 0.f ? -t : t;
}

// ===========================================================================
// f32 GEMM engine v5: round-13 structure (single-buffered, conflict-free
// B mapping) with BK=32 slabs: halves barrier count (64->32 per K=512).
// Staging regs are consumed immediately (short live range — unlike the
// rejected r12/r14 prefetch variants that spanned the FMA loop).
// C[M][N] = act(A[M][K] @ Bt[N][K]^T + bias). M,N %128==0, K %32==0.
// ===========================================================================
template<int ACT>   // 0 none, 1 relu, 2 sigmoid
__global__ __launch_bounds__(256)
void k_fgemm(const float* __restrict__ A, int lda,
             const float* __restrict__ Bt, int ldb,
             const float* __restrict__ bias,
             float* __restrict__ C, int ldc, int K)
{
    __shared__ float As[32][132];
    __shared__ float Bs[32][132];
    const int t = threadIdx.x;
    const int tx = t & 15, ty = t >> 4;
    const long brow = (long)blockIdx.y * 128;
    const long bcol = (long)blockIdx.x * 128;
    const int sr = t >> 1;              // staging row 0..127
    const int kq = (t & 1) * 16;        // staging k offset 0/16

    f32x2 acc[8][4];
#pragma unroll
    for (int i = 0; i < 8; ++i)
#pragma unroll
        for (int j = 0; j < 4; ++j) acc[i][j] = (f32x2){0.f, 0.f};

    for (int kt = 0; kt < K; kt += 32) {
        const float* pa = A  + (brow + sr) * (long)lda + kt + kq;
        const float* pb = Bt + (bcol + sr) * (long)ldb + kt + kq;
        float4 a0 = *(const float4*)(pa);
        float4 a1 = *(const float4*)(pa + 4);
        float4 a2 = *(const float4*)(pa + 8);
        float4 a3 = *(const float4*)(pa + 12);
        float4 b0 = *(const float4*)(pb);
        float4 b1 = *(const float4*)(pb + 4);
        float4 b2 = *(const float4*)(pb + 8);
        float4 b3 = *(const float4*)(pb + 12);
        As[kq +  0][sr] = a0.x; As[kq +  1][sr] = a0.y; As[kq +  2][sr] = a0.z; As[kq +  3][sr] = a0.w;
        As[kq +  4][sr] = a1.x; As[kq +  5][sr] = a1.y; As[kq +  6][sr] = a1.z; As[kq +  7][sr] = a1.w;
        As[kq +  8][sr] = a2.x; As[kq +  9][sr] = a2.y; As[kq + 10][sr] = a2.z; As[kq + 11][sr] = a2.w;
        As[kq + 12][sr] = a3.x; As[kq + 13][sr] = a3.y; As[kq + 14][sr] = a3.z; As[kq + 15][sr] = a3.w;
        Bs[kq +  0][sr] = b0.x; Bs[kq +  1][sr] = b0.y; Bs[kq +  2][sr] = b0.z; Bs[kq +  3][sr] = b0.w;
        Bs[kq +  4][sr] = b1.x; Bs[kq +  5][sr] = b1.y; Bs[kq +  6][sr] = b1.z; Bs[kq +  7][sr] = b1.w;
        Bs[kq +  8][sr] = b2.x; Bs[kq +  9][sr] = b2.y; Bs[kq + 10][sr] = b2.z; Bs[kq + 11][sr] = b2.w;
        Bs[kq + 12][sr] = b3.x; Bs[kq + 13][sr] = b3.y; Bs[kq + 14][sr] = b3.z; Bs[kq + 15][sr] = b3.w;
        __syncthreads();
#pragma unroll
        for (int kk = 0; kk < 32; ++kk) {
            float av[8], bv[8];
            *(float4*)&av[0] = *(const float4*)&As[kk][ty * 8];
            *(float4*)&av[4] = *(const float4*)&As[kk][ty * 8 + 4];
            *(float4*)&bv[0] = *(const float4*)&Bs[kk][tx * 4];        // 2-way (free)
            *(float4*)&bv[4] = *(const float4*)&Bs[kk][tx * 4 + 64];   // 2-way (free)
#pragma unroll
            for (int i = 0; i < 8; ++i) {
                const f32x2 ai = {av[i], av[i]};
#pragma unroll
                for (int j = 0; j < 4; ++j) {
                    const f32x2 bj = {bv[j * 2], bv[j * 2 + 1]};
                    acc[i][j].x = fmaf(ai.x, bj.x, acc[i][j].x);
                    acc[i][j].y = fmaf(ai.y, bj.y, acc[i][j].y);
                }
            }
        }
        __syncthreads();
    }

    // cols: bcol + tx*4 + {0,64} + (j&3)
    float bb[8];
#pragma unroll
    for (int j = 0; j < 8; ++j)
        bb[j] = bias ? bias[bcol + tx * 4 + (j >> 2) * 64 + (j & 3)] : 0.f;
#pragma unroll
    for (int i = 0; i < 8; ++i) {
        float o[8];
#pragma unroll
        for (int j = 0; j < 4; ++j) { o[j * 2] = acc[i][j].x; o[j * 2 + 1] = acc[i][j].y; }
        float r[8];
#pragma unroll
        for (int j = 0; j < 8; ++j) {
            float v = o[j] + bb[j];
            if (ACT == 1) v = fmaxf(v, 0.f);
            if (ACT == 2) v = sigm(v);
            r[j] = v;
        }
        float* cp = C + (brow + ty * 8 + i) * (long)ldc + bcol + tx * 4;
        *(float4*)cp = *(const float4*)&r[0];
        *(float4*)(cp + 64) = *(const float4*)&r[4];
    }
}

// fp32 [K][N] -> fp32 [N][K] transpose (weights -> Bt layout)
__global__ __launch_bounds__(256)
void k_transposeF(const float* __restrict__ W, float* __restrict__ Wt, int K, int N)
{
    __shared__ float tile[32][33];
    const int n0 = blockIdx.x * 32, k0 = blockIdx.y * 32;
    const int tx = threadIdx.x & 31, ty = threadIdx.x >> 5;
#pragma unroll
    for (int r = 0; r < 4; ++r)
        tile[ty + r * 8][tx] = W[(long)(k0 + ty + r * 8) * N + n0 + tx];
    __syncthreads();
#pragma unroll
    for (int r = 0; r < 4; ++r)
        Wt[(long)(n0 + ty + r * 8) * K + k0 + tx] = tile[tx][ty + r * 8];
}

// f32 copy with output leading dim (features -> gcat[:,512:1536])
__global__ void k_copyF(const float* __restrict__ s, float* __restrict__ d, int C, int ldd)
{
    const long idx = ((long)blockIdx.x * 256 + threadIdx.x) * 4;
    const long r = idx / C; const int c = (int)(idx % C);
    *(float4*)(d + r * (long)ldd + c) = *(const float4*)(s + r * (long)C + c);
}

// embedding gather: hcat[row][0:512] = hcat[row][512:1024] = embed_W[tok]
__global__ void k_embedF(const int* __restrict__ at, const float* __restrict__ ew,
                         float* __restrict__ hcat)
{
    const long idx = (long)blockIdx.x * 256 + threadIdx.x;
    const long row = idx >> 6; const int c8 = (int)(idx & 63) * 8;
    const int tok = at[row];
    const float4 v0 = *(const float4*)(ew + (long)tok * 512 + c8);
    const float4 v1 = *(const float4*)(ew + (long)tok * 512 + c8 + 4);
    float* o = hcat + row * 1024 + c8;
    *(float4*)o = v0;           *(float4*)(o + 4) = v1;
    *(float4*)(o + 512) = v0;   *(float4*)(o + 516) = v1;
}

// sparse edge-typed einsum (round-3 proven):
// mout[n*64+i][h] = sum_{e,j: adj[n,e,i,j]!=0} msg[n*64+j][e*512+h]
__global__ __launch_bounds__(256)
void k_einsum_s(const float* __restrict__ adj, const float* __restrict__ msg,
                float* __restrict__ mout)
{
    const int b = blockIdx.x;
    const int n = b >> 6, i = b & 63;
    const int t = threadIdx.x;
    float a0 = 0.f, a1 = 0.f;
#pragma unroll
    for (int e = 0; e < 4; ++e) {
        const float* ar = adj + (((long)n * 4 + e) * 64 + i) * 64;
        const float* me = msg + (long)n * 64 * 2048 + e * 512;
        for (int j = 0; j < 64; ++j) {
            if (ar[j] != 0.f) {
                const float* mr = me + (long)j * 2048;
                a0 += mr[t]; a1 += mr[t + 256];
            }
        }
    }
    mout[(long)b * 512 + t] = a0;
    mout[(long)b * 512 + t + 256] = a1;
}

// GRU elementwise (f32); h kept in hcat[:,0:512]
template<int STEP0>
__global__ __launch_bounds__(256)
void k_gruF(const float* __restrict__ gi, const float* __restrict__ gh,
            const float* __restrict__ bhh, float* __restrict__ hcat)
{
    const long idx = (long)blockIdx.x * 256 + threadIdx.x;
    const long row = idx >> 7; const int c4 = (int)(idx & 127) * 4;
    const float* gir = gi + row * 1536 + c4;
    const float4 xr = *(const float4*)(gir);
    const float4 xz = *(const float4*)(gir + 512);
    const float4 xn = *(const float4*)(gir + 1024);
    float* hp = hcat + row * 1024 + c4;
    const float4 hv = *(const float4*)hp;
    float4 hr, hz, hn;
    if (STEP0) {
        hr = *(const float4*)(bhh + c4);
        hz = *(const float4*)(bhh + 512 + c4);
        hn = *(const float4*)(bhh + 1024 + c4);
    } else {
        const float* ghr = gh + row * 1536 + c4;
        hr = *(const float4*)(ghr);
        hz = *(const float4*)(ghr + 512);
        hn = *(const float4*)(ghr + 1024);
    }
    const float xra[4] = {xr.x, xr.y, xr.z, xr.w};
    const float xza[4] = {xz.x, xz.y, xz.z, xz.w};
    const float xna[4] = {xn.x, xn.y, xn.z, xn.w};
    const float hra[4] = {hr.x, hr.y, hr.z, hr.w};
    const float hza[4] = {hz.x, hz.y, hz.z, hz.w};
    const float hna[4] = {hn.x, hn.y, hn.z, hn.w};
    const float hva[4] = {hv.x, hv.y, hv.z, hv.w};
    float o[4];
#pragma unroll
    for (int k = 0; k < 4; ++k) {
        const float hprev = STEP0 ? 0.f : hva[k];
        const float r = sigm(xra[k] + hra[k]);
        const float z = sigm(xza[k] + hza[k]);
        const float nn = tanh_fast(xna[k] + r * hna[k]);
        o[k] = (1.f - z) * nn + z * hprev;
    }
    float4 ov; ov.x = o[0]; ov.y = o[1]; ov.z = o[2]; ov.w = o[3];
    *(float4*)hp = ov;
}

// readout: g[n,h] = (65/128) * sum_a gate[n*64+a][h]*jj[n*64+a][h]
__global__ __launch_bounds__(256)
void k_readout(const float* __restrict__ gate, const float* __restrict__ jj, float* __restrict__ g)
{
    const int n = blockIdx.x, t = threadIdx.x;
    float a0 = 0.f, a1 = 0.f;
    for (int a = 0; a < 64; ++a) {
        const long base = ((long)n * 64 + a) * 512;
        a0 += gate[base + t] * jj[base + t];
        a1 += gate[base + t + 256] * jj[base + t + 256];
    }
    g[(long)n * 512 + t]       = a0 * (65.f / 128.f);
    g[(long)n * 512 + t + 256] = a1 * (65.f / 128.f);
}

// attention fusion over the two views -> fused f32 [1024][512]
__global__ __launch_bounds__(128)
void k_att(const float* __restrict__ g, const float* __restrict__ emb,
           const float* __restrict__ W1, const float* __restrict__ bias1,
           const float* __restrict__ W2, float* __restrict__ fused)
{
    __shared__ float v[512];
    __shared__ float red[128];
    __shared__ float sres[2];
    const int n = blockIdx.x, t = threadIdx.x;
    for (int view = 0; view < 2; ++view) {
        const float* src = (view ? emb : g) + (long)n * 512;
        for (int k = t; k < 512; k += 128) v[k] = src[k];
        __syncthreads();
        float acc = bias1[t];
        for (int k = 0; k < 512; ++k) acc += v[k] * W1[k * 128 + t];
        red[t] = tanh_fast(acc) * W2[t];
        __syncthreads();
        if (t == 0) { float s = 0.f; for (int i = 0; i < 128; ++i) s += red[i]; sres[view] = s; }
        __syncthreads();
    }
    const float b0 = 1.f / (1.f + __expf(sres[1] - sres[0]));
    const float b1v = 1.f - b0;
    for (int k = t; k < 512; k += 128) {
        fused[(long)n * 512 + k] = b0 * g[(long)n * 512 + k] + b1v * emb[(long)n * 512 + k];
    }
}

// ===========================================================================
// host side
// ===========================================================================
static void sgemm(hipStream_t st, const float* A, int lda, const float* B, int ldb,
                  const float* bias, float* C, int ldc, int M, int N, int K, int act)
{
    dim3 g(N / 128, M / 128), b(256);
    if (act == 0)      k_fgemm<0><<<g, b, 0, st>>>(A, lda, B, ldb, bias, C, ldc, K);
    else if (act == 1) k_fgemm<1><<<g, b, 0, st>>>(A, lda, B, ldb, bias, C, ldc, K);
    else               k_fgemm<2><<<g, b, 0, st>>>(A, lda, B, ldb, bias, C, ldc, K);
}

extern "C" void kernel_launch(void* const* d_in, const int* in_sizes, int n_in,
                              void* d_out, int out_size, void* d_ws, size_t ws_size,
                              hipStream_t stream)
{
    const int*   atom = (const int*)  d_in[0];
    const float* adj  = (const float*)d_in[1];
    const float* feat = (const float*)d_in[2];
    const float* adjn = (const float*)d_in[3];
    const float* embW = (const float*)d_in[4];
    const float* msgW = (const float*)d_in[5];
    const float* msgb = (const float*)d_in[6];
    const float* Wih  = (const float*)d_in[7];
    const float* Whh  = (const float*)d_in[8];
    const float* bih  = (const float*)d_in[9];
    const float* bhh  = (const float*)d_in[10];
    const float* iW   = (const float*)d_in[11];
    const float* ib   = (const float*)d_in[12];
    const float* jW   = (const float*)d_in[13];
    const float* jb   = (const float*)d_in[14];
    const float* gc1  = (const float*)d_in[15];
    const float* gc2  = (const float*)d_in[16];
    const float* gc3  = (const float*)d_in[17];
    const float* thW  = (const float*)d_in[18];
    const float* thb  = (const float*)d_in[19];
    const float* th1W = (const float*)d_in[20];
    const float* th1b = (const float*)d_in[21];
    const float* th2W = (const float*)d_in[22];
    const float* th2b = (const float*)d_in[23];
    const float* aW1  = (const float*)d_in[24];
    const float* ab1  = (const float*)d_in[25];
    const float* aW2  = (const float*)d_in[26];

    // ---- fixed workspace region (identical to passing round 13/15) ----
    constexpr size_t O_WTMSG = 0;
    constexpr size_t O_WTWIH = O_WTMSG + (size_t)3 * 2048 * 512 * 4;
    constexpr size_t O_WTWHH = O_WTWIH + (size_t)1536 * 512 * 4;
    constexpr size_t O_WTIW  = O_WTWHH + (size_t)1536 * 512 * 4;
    constexpr size_t O_WTJW  = O_WTIW  + (size_t)512 * 1024 * 4;
    constexpr size_t O_WTGC1 = O_WTJW  + (size_t)512 * 512 * 4;
    constexpr size_t O_WTGC2 = O_WTGC1 + (size_t)512 * 1024 * 4;
    constexpr size_t O_WTGC3 = O_WTGC2 + (size_t)512 * 512 * 4;
    constexpr size_t O_WTTH  = O_WTGC3 + (size_t)512 * 512 * 4;
    constexpr size_t O_WTTH1 = O_WTTH  + (size_t)512 * 1536 * 4;
    constexpr size_t O_WTTH2 = O_WTTH1 + (size_t)512 * 1536 * 4;
    constexpr size_t O_GCAT  = O_WTTH2 + (size_t)512 * 1536 * 4;
    constexpr size_t O_PT    = O_GCAT  + (size_t)1024 * 1536 * 4;
    constexpr size_t O_H1    = O_PT    + (size_t)512 * 1024 * 4;
    constexpr size_t O_H2    = O_H1    + (size_t)1024 * 512 * 4;
    constexpr size_t O_EMBF  = O_H2    + (size_t)1024 * 512 * 4;
    constexpr size_t O_GF    = O_EMBF  + (size_t)1024 * 512 * 4;
    constexpr size_t O_FUSED = O_GF    + (size_t)1024 * 512 * 4;
    constexpr size_t O_CHUNK = O_FUSED + (size_t)1024 * 512 * 4;

    // per-atom-row chunk bytes: hcat 4096 + gh 6144 + magg 2048 + msg 8192 = 20480
    int C = 1024;
    while (C > 2 && O_CHUNK + (size_t)64 * C * 20480 > ws_size) C >>= 1;
    if (O_CHUNK + (size_t)64 * C * 20480 > ws_size) return;
    const int R = C * 64;
    const int nchunks = 1024 / C;

    uint8_t* wsb = (uint8_t*)d_ws;
    float* wtMsg = (float*)(wsb + O_WTMSG);
    float* wtWih = (float*)(wsb + O_WTWIH);
    float* wtWhh = (float*)(wsb + O_WTWHH);
    float* wtIw  = (float*)(wsb + O_WTIW);
    float* wtJw  = (float*)(wsb + O_WTJW);
    float* wtGc1 = (float*)(wsb + O_WTGC1);
    float* wtGc2 = (float*)(wsb + O_WTGC2);
    float* wtGc3 = (float*)(wsb + O_WTGC3);
    float* wtTh  = (float*)(wsb + O_WTTH);
    float* wtTh1 = (float*)(wsb + O_WTTH1);
    float* wtTh2 = (float*)(wsb + O_WTTH2);
    float* gcatF = (float*)(wsb + O_GCAT);
    float* ptF   = (float*)(wsb + O_PT);
    float* h1F   = (float*)(wsb + O_H1);
    float* h2F   = (float*)(wsb + O_H2);
    float* embF  = (float*)(wsb + O_EMBF);
    float* gF    = (float*)(wsb + O_GF);
    float* fusedF= (float*)(wsb + O_FUSED);
    uint8_t* cr = wsb + O_CHUNK;
    float* hcatF = (float*)(cr);
    float* ghF   = (float*)(cr + (size_t)R * 4096);
    float* maggF = (float*)(cr + (size_t)R * 10240);
    float* msgF  = (float*)(cr + (size_t)R * 12288);
    float* giF   = msgF;                                   // alias: msg dead when gi written
    float* gateF = msgF;                                   // alias: post-GRU phase
    float* jjF   = msgF + (size_t)R * 512;

    // ---- weight prep (f32 transposed to Bt [N][K]) — once ----
    for (int s = 0; s < 3; ++s)
        k_transposeF<<<dim3(64, 16), 256, 0, stream>>>(msgW + (size_t)s * 512 * 2048,
                                                       wtMsg + (size_t)s * 2048 * 512, 512, 2048);
    k_transposeF<<<dim3(48, 16), 256, 0, stream>>>(Wih, wtWih, 512, 1536);
    k_transposeF<<<dim3(48, 16), 256, 0, stream>>>(Whh, wtWhh, 512, 1536);
    k_transposeF<<<dim3(16, 32), 256, 0, stream>>>(iW,  wtIw, 1024, 512);
    k_transposeF<<<dim3(16, 16), 256, 0, stream>>>(jW,  wtJw,  512, 512);
    k_transposeF<<<dim3(16, 32), 256, 0, stream>>>(gc1, wtGc1, 1024, 512);
    k_transposeF<<<dim3(16, 16), 256, 0, stream>>>(gc2, wtGc2, 512, 512);
    k_transposeF<<<dim3(16, 16), 256, 0, stream>>>(gc3, wtGc3, 512, 512);
    k_transposeF<<<dim3(16, 48), 256, 0, stream>>>(thW,  wtTh,  1536, 512);
    k_transposeF<<<dim3(16, 48), 256, 0, stream>>>(th1W, wtTh1, 1536, 512);
    k_transposeF<<<dim3(16, 48), 256, 0, stream>>>(th2W, wtTh2, 1536, 512);
    k_copyF<<<1024, 256, 0, stream>>>(feat, gcatF + 512, 1024, 1536);

    // ---- GGNN + readout, chunked over molecules ----
    for (int c = 0; c < nchunks; ++c) {
        const size_t arow0 = (size_t)c * R;
        k_embedF<<<R / 4, 256, 0, stream>>>(atom + arow0, embW, hcatF);
        for (int s = 0; s < 3; ++s) {
            sgemm(stream, hcatF, 1024, wtMsg + (size_t)s * 2048 * 512, 512,
                  msgb + (size_t)s * 2048, msgF, 2048, R, 2048, 512, 0);
            k_einsum_s<<<R, 256, 0, stream>>>(adj + (size_t)c * C * 4 * 64 * 64, msgF, maggF);
            sgemm(stream, maggF, 512, wtWih, 512, bih, giF, 1536, R, 1536, 512, 0);
            if (s > 0)
                sgemm(stream, hcatF, 1024, wtWhh, 512, bhh, ghF, 1536, R, 1536, 512, 0);
            if (s == 0) k_gruF<1><<<R / 2, 256, 0, stream>>>(giF, nullptr, bhh, hcatF);
            else        k_gruF<0><<<R / 2, 256, 0, stream>>>(giF, ghF, bhh, hcatF);
        }
        sgemm(stream, hcatF, 1024, wtIw, 1024, ib, gateF, 512, R, 512, 1024, 2);
        sgemm(stream, hcatF, 1024, wtJw,  512, jb, jjF,   512, R, 512,  512, 0);
        k_readout<<<C, 256, 0, stream>>>(gateF, jjF, gF + (size_t)c * C * 512);
    }

    // ---- GCN drug encoder ----
    sgemm(stream, wtGc1, 1024, feat, 1024, nullptr, ptF, 1024, 512, 1024, 1024, 0);
    sgemm(stream, adjn, 1024, ptF, 1024, nullptr, gcatF, 1536, 1024, 512, 1024, 0);
    sgemm(stream, gcatF, 1536, wtTh, 1536, thb, h1F, 512, 1024, 512, 1536, 1);
    sgemm(stream, wtGc2, 512, h1F, 512, nullptr, ptF, 1024, 512, 1024, 512, 0);
    sgemm(stream, adjn, 1024, ptF, 1024, nullptr, gcatF, 1536, 1024, 512, 1024, 0);
    sgemm(stream, gcatF, 1536, wtTh1, 1536, th1b, h2F, 512, 1024, 512, 1536, 1);
    sgemm(stream, wtGc3, 512, h2F, 512, nullptr, ptF, 1024, 512, 1024, 512, 0);
    sgemm(stream, adjn, 1024, ptF, 1024, nullptr, gcatF, 1536, 1024, 512, 1024, 0);
    sgemm(stream, gcatF, 1536, wtTh2, 1536, th2b, embF, 512, 1024, 512, 1536, 1);

    // ---- attention fusion + inner-product decoder ----
    k_att<<<1024, 128, 0, stream>>>(gF, embF, aW1, ab1, aW2, fusedF);
    sgemm(stream, fusedF, 512, fusedF, 512, nullptr, (float*)d_out, 1024, 1024, 1024, 512, 2);
}